// Round 2
// baseline (75.443 us; speedup 1.0000x reference)
//
#include <hip/hip_runtime.h>
#include <hip/hip_bf16.h>
#include <cstdint>

// B=32,S=2048,F=16,H=64,E=256.  BS=65536 rows.
// out[r,e] = sum_f ( mask[r,f] ? mv[f,e] : dot(gelu(x[r,f]*W1[f,:]+b1[f,:]), W2[f,e,:]) + b2[f,e] )
// One GEMM [BS x (16*64+32)] x [.. x 256]; chunk 16 carries (mask->mv-b2) and (1->sum b2).
// Per-feature B chunks pre-permuted (bf16, inverse-swizzled) so global_load_lds stages them
// linearly and ds_read applies the XOR swizzle.  A/B double-buffered, 1 barrier/iter.

#define F_ 16
#define H_ 64
#define E_ 256
#define BM 128
#define NT 512
#define BS_TOTAL 65536
#define NCHUNK 17
#define CHUNK_BYTES 32768   // 256 e x 64 k x 2B

typedef __attribute__((ext_vector_type(8))) short s16x8;
typedef __attribute__((ext_vector_type(4))) float f32x4;

typedef const __attribute__((address_space(1))) unsigned int* gas_ptr;
typedef __attribute__((address_space(3))) unsigned int* las_ptr;

__device__ __forceinline__ unsigned short f2bf(float f){
  unsigned u = __builtin_bit_cast(unsigned, f);
  u += 0x7FFFu + ((u >> 16) & 1u);
  return (unsigned short)(u >> 16);
}
__device__ __forceinline__ unsigned cvtpk(float a, float b){
  unsigned r; asm("v_cvt_pk_bf16_f32 %0, %1, %2" : "=v"(r) : "v"(a), "v"(b)); return r;
}
// tanh-form gelu: t*sigmoid(2.302208*t + 0.1029432*t^3), abs err ~3e-4
__device__ __forceinline__ float gelu_f(float t){
  float t2 = t * t;
  float g2 = fmaf(t2, 0.10294324f, 2.3022082f) * t;
  float e  = __builtin_amdgcn_exp2f(g2);
  float r  = __builtin_amdgcn_rcpf(1.0f + e);
  return t - t * r;
}

// W2 [16][256][64] f32 -> 16 chunks of [256 e][64 h] bf16, 16B-slot c holds
// (e=c>>3, h-chunk hc=(c&7)^(e&7)) so a linear LDS copy + XOR-swizzled read works.
__global__ void prep_w2(const float* __restrict__ W2, unsigned short* __restrict__ W2s){
  int idx = blockIdx.x * 256 + threadIdx.x;      // 0..32767
  int f = idx >> 11, c = idx & 2047;
  int e = c >> 3, hc = (c & 7) ^ (e & 7);
  const float4* src = (const float4*)(W2 + ((f * E_ + e) * H_ + hc * 8));
  float4 v0 = src[0], v1 = src[1];
  unsigned u[4];
  u[0] = (unsigned)f2bf(v0.x) | ((unsigned)f2bf(v0.y) << 16);
  u[1] = (unsigned)f2bf(v0.z) | ((unsigned)f2bf(v0.w) << 16);
  u[2] = (unsigned)f2bf(v1.x) | ((unsigned)f2bf(v1.y) << 16);
  u[3] = (unsigned)f2bf(v1.z) | ((unsigned)f2bf(v1.w) << 16);
  *(uint4*)((char*)W2s + f * CHUNK_BYTES + c * 16) = *(uint4*)u;
}

// chunk 16: k<16 -> mv[k][e]-b2[k][e], k==16 -> sum_f b2[f][e], else 0
__global__ void prep_tail(const float* __restrict__ b2, const float* __restrict__ mv,
                          unsigned short* __restrict__ W2s){
  int c = blockIdx.x * 256 + threadIdx.x;        // 0..2047
  int e = c >> 3, hc = (c & 7) ^ (e & 7);
  unsigned short ov[8];
  #pragma unroll
  for (int j = 0; j < 8; ++j){
    int k = hc * 8 + j;
    float v = 0.f;
    if (k < 16) v = mv[k * E_ + e] - b2[k * E_ + e];
    else if (k == 16){ float s = 0.f; for (int f = 0; f < F_; ++f) s += b2[f * E_ + e]; v = s; }
    ov[j] = f2bf(v);
  }
  *(uint4*)((char*)W2s + 16 * CHUNK_BYTES + c * 16) = *(uint4*)ov;
}

__global__ __launch_bounds__(NT, 2)
void ts_embed_main(const float* __restrict__ x, const int* __restrict__ mask,
                   const float* __restrict__ W1, const float* __restrict__ b1,
                   const unsigned short* __restrict__ W2s,
                   float* __restrict__ out){
  __shared__ __align__(16) short Abuf[2][BM * H_];   // 2 x 16 KB, swizzled
  __shared__ __align__(16) short Bbuf[2][E_ * H_];   // 2 x 32 KB, swizzled
  __shared__ __align__(16) float w1s[F_ * H_];
  __shared__ __align__(16) float b1s[F_ * H_];
  __shared__ __align__(16) float xs[BM * F_];
  __shared__ unsigned mrow[BM];

  const int tid  = threadIdx.x;
  const int lane = tid & 63;
  const int wid  = tid >> 6;
  const int wm   = wid >> 2, wn = wid & 3;
  const int rr   = lane & 15;
  const int klo  = (lane >> 4) << 3;
  const long rowBase = (long)blockIdx.x * BM;

  // ---- prologue staging
  ((float4*)xs)[tid] = ((const float4*)(x + rowBase * F_))[tid];
  if (tid < 256)      ((float4*)w1s)[tid]       = ((const float4*)W1)[tid];
  else                ((float4*)b1s)[tid - 256] = ((const float4*)b1)[tid - 256];
  if (tid < BM){
    const int4* mg = (const int4*)(mask + (rowBase + tid) * F_);
    unsigned bits = 0;
    #pragma unroll
    for (int q = 0; q < 4; ++q){
      int4 m = mg[q];
      bits |= (m.x != 0 ? 1u : 0u) << (q * 4 + 0);
      bits |= (m.y != 0 ? 1u : 0u) << (q * 4 + 1);
      bits |= (m.z != 0 ? 1u : 0u) << (q * 4 + 2);
      bits |= (m.w != 0 ? 1u : 0u) << (q * 4 + 3);
    }
    mrow[tid] = bits;
  }
  __syncthreads();

  const int r0 = tid >> 3, hcw = tid & 7;          // this thread's A rows: r0, r0+64
  const unsigned mb0 = mrow[r0], mb1 = mrow[r0 + 64];

  // async-stage chunk -> Bbuf[buf] (linear copy; 4 x 16B per thread)
  auto stageB = [&](int chunk, int buf){
    const char* src = (const char*)W2s + chunk * CHUNK_BYTES + wid * 1024 + lane * 16;
    char* dst = (char*)Bbuf[0] + buf * (E_ * H_ * 2) + wid * 1024;
    #pragma unroll
    for (int kq = 0; kq < 4; ++kq)
      __builtin_amdgcn_global_load_lds((gas_ptr)(src + kq * 8192), (las_ptr)(dst + kq * 8192), 16, 0, 0);
  };

  // compute A chunk fn into Abuf[buf] (fn==16 -> mask/ones tail)
  auto computeA = [&](int fn, int buf){
    char* Ab = (char*)Abuf[0] + buf * (BM * H_ * 2);
    #pragma unroll
    for (int half = 0; half < 2; ++half){
      int r = r0 + half * 64;
      unsigned mb = half ? mb1 : mb0;
      float g[8];
      if (fn < F_){
        float xv  = xs[r * F_ + fn];
        float sel = ((mb >> fn) & 1u) ? 0.0f : 1.0f;
        const float4* wp = (const float4*)&w1s[fn * H_ + hcw * 8];
        const float4* bp = (const float4*)&b1s[fn * H_ + hcw * 8];
        float4 w0 = wp[0], w1v = wp[1], c0 = bp[0], c1 = bp[1];
        g[0] = sel * gelu_f(fmaf(xv, w0.x,  c0.x));
        g[1] = sel * gelu_f(fmaf(xv, w0.y,  c0.y));
        g[2] = sel * gelu_f(fmaf(xv, w0.z,  c0.z));
        g[3] = sel * gelu_f(fmaf(xv, w0.w,  c0.w));
        g[4] = sel * gelu_f(fmaf(xv, w1v.x, c1.x));
        g[5] = sel * gelu_f(fmaf(xv, w1v.y, c1.y));
        g[6] = sel * gelu_f(fmaf(xv, w1v.z, c1.z));
        g[7] = sel * gelu_f(fmaf(xv, w1v.w, c1.w));
      } else {
        #pragma unroll
        for (int j = 0; j < 8; ++j){
          int k = hcw * 8 + j;
          g[j] = (k < 16) ? (float)((mb >> k) & 1u) : (k == 16 ? 1.0f : 0.0f);
        }
      }
      union { unsigned u[4]; s16x8 v; } pk;
      pk.u[0] = cvtpk(g[0], g[1]); pk.u[1] = cvtpk(g[2], g[3]);
      pk.u[2] = cvtpk(g[4], g[5]); pk.u[3] = cvtpk(g[6], g[7]);
      int byte = (r * 128 + hcw * 16) ^ ((r & 7) << 4);
      *(s16x8*)(Ab + byte) = pk.v;
    }
  };

  // ---- prologue pipeline fill
  stageB(0, 0);
  computeA(0, 0);
  __syncthreads();                        // drains vmcnt: B[0] resident, A[0] written

  f32x4 acc[4][4] = {};

  for (int f = 0; f < NCHUNK; ++f){
    if (f < NCHUNK - 1){
      stageB(f + 1, (f + 1) & 1);         // async, lands before next barrier
      computeA(f + 1, (f + 1) & 1);       // VALU overlaps B load + MFMA below
    }
    const char* Ab = (const char*)Abuf[0] + (f & 1) * (BM * H_ * 2);
    const char* Bb = (const char*)Bbuf[0] + (f & 1) * (E_ * H_ * 2);
    #pragma unroll
    for (int kk = 0; kk < 2; ++kk){
      s16x8 af[4], bfr[4];
      #pragma unroll
      for (int m = 0; m < 4; ++m){
        int r = wm * 64 + m * 16 + rr;
        int byte = (r * 128 + (kk * 32 + klo) * 2) ^ ((r & 7) << 4);
        af[m] = *(const s16x8*)(Ab + byte);
      }
      #pragma unroll
      for (int n = 0; n < 4; ++n){
        int e = wn * 64 + n * 16 + rr;
        int byte = (e * 128 + (kk * 32 + klo) * 2) ^ ((e & 7) << 4);
        bfr[n] = *(const s16x8*)(Bb + byte);
      }
      #pragma unroll
      for (int m = 0; m < 4; ++m)
        #pragma unroll
        for (int n = 0; n < 4; ++n)
          acc[m][n] = __builtin_amdgcn_mfma_f32_16x16x32_bf16(af[m], bfr[n], acc[m][n], 0, 0, 0);
    }
    __syncthreads();
  }

  // ---- epilogue (bias+mask already folded via chunk 16)
  const int rg = lane >> 4;
  #pragma unroll
  for (int m = 0; m < 4; ++m){
    #pragma unroll
    for (int n = 0; n < 4; ++n){
      int e = wn * 64 + n * 16 + rr;
      long r = rowBase + wm * 64 + m * 16 + rg * 4;
      #pragma unroll
      for (int j = 0; j < 4; ++j)
        out[(r + j) * E_ + e] = acc[m][n][j];
    }
  }
}

extern "C" void kernel_launch(void* const* d_in, const int* in_sizes, int n_in,
                              void* d_out, int out_size, void* d_ws, size_t ws_size,
                              hipStream_t stream) {
  const float* x    = (const float*)d_in[0];
  const int*   mask = (const int*)d_in[1];
  const float* W1   = (const float*)d_in[2];
  const float* b1   = (const float*)d_in[3];
  const float* W2   = (const float*)d_in[4];
  const float* b2   = (const float*)d_in[5];
  const float* mv   = (const float*)d_in[6];
  float* out = (float*)d_out;

  unsigned short* W2s = (unsigned short*)d_ws;   // 17 * 32768 = 557056 B

  prep_w2<<<dim3(128), dim3(256), 0, stream>>>(W2, W2s);
  prep_tail<<<dim3(8), dim3(256), 0, stream>>>(b2, mv, W2s);
  ts_embed_main<<<dim3(BS_TOTAL / BM), dim3(NT), 0, stream>>>(x, mask, W1, b1, W2s, out);
}

// Round 3
// 75.280 us; speedup vs baseline: 1.0022x; 1.0022x over previous
//
#include <hip/hip_runtime.h>
#include <hip/hip_bf16.h>
#include <cstdint>

// B=32,S=2048,F=16,H=64,E=256.  BS=65536 rows.
// out[r,e] = sum_f ( mask[r,f] ? mv[f,e] : dot(gelu(x[r,f]*W1[f,:]+b1[f,:]), W2[f,e,:]) + b2[f,e] )
// One GEMM [BS x (16*64+32)] x [.. x 256]; chunk 16 carries (mask->mv-b2, 1->sum b2).
// r3: single barrier per feature; A and B double-buffered; B staged via global_load_lds
// from pre-swizzled bf16 W2s; gelu(f+1) + DMA(f+1) + MFMA(f) share one barrier interval.

#define F_ 16
#define H_ 64
#define E_ 256
#define BM 128
#define NT 512
#define BS_TOTAL 65536
#define NCHUNK 17
#define CHUNK_BYTES 32768   // 256 e x 64 k x 2B

typedef __attribute__((ext_vector_type(8))) short s16x8;
typedef __attribute__((ext_vector_type(4))) float f32x4;

typedef const __attribute__((address_space(1))) unsigned int* gas_ptr;
typedef __attribute__((address_space(3))) unsigned int* las_ptr;

__device__ __forceinline__ unsigned short f2bf(float f){
  unsigned u = __builtin_bit_cast(unsigned, f);
  u += 0x7FFFu + ((u >> 16) & 1u);
  return (unsigned short)(u >> 16);
}
__device__ __forceinline__ unsigned cvtpk(float a, float b){
  unsigned r; asm("v_cvt_pk_bf16_f32 %0, %1, %2" : "=v"(r) : "v"(a), "v"(b)); return r;
}
// tanh-form gelu: abs err ~3e-4
__device__ __forceinline__ float gelu_f(float t){
  float t2 = t * t;
  float g2 = fmaf(t2, 0.10294324f, 2.3022082f) * t;
  float e  = __builtin_amdgcn_exp2f(g2);
  float r  = __builtin_amdgcn_rcpf(1.0f + e);
  return t - t * r;
}

// W2 [16][256][64] f32 -> 16 chunks of [256][64] bf16, slot c=(e,hc) pre-inverse-swizzled
// so linear LDS copy + XOR-swizzled ds_read works.
__global__ void prep_w2(const float* __restrict__ W2, unsigned short* __restrict__ W2s){
  int idx = blockIdx.x * 256 + threadIdx.x;      // 0..32767
  int f = idx >> 11, c = idx & 2047;
  int e = c >> 3, hc = (c & 7) ^ (e & 7);
  const float4* src = (const float4*)(W2 + ((f * E_ + e) * H_ + hc * 8));
  float4 v0 = src[0], v1 = src[1];
  unsigned u[4];
  u[0] = (unsigned)f2bf(v0.x) | ((unsigned)f2bf(v0.y) << 16);
  u[1] = (unsigned)f2bf(v0.z) | ((unsigned)f2bf(v0.w) << 16);
  u[2] = (unsigned)f2bf(v1.x) | ((unsigned)f2bf(v1.y) << 16);
  u[3] = (unsigned)f2bf(v1.z) | ((unsigned)f2bf(v1.w) << 16);
  *(uint4*)((char*)W2s + f * CHUNK_BYTES + c * 16) = *(uint4*)u;
}

__global__ void prep_tail(const float* __restrict__ b2, const float* __restrict__ mv,
                          unsigned short* __restrict__ W2s){
  int c = blockIdx.x * 256 + threadIdx.x;        // 0..2047
  int e = c >> 3, hc = (c & 7) ^ (e & 7);
  unsigned short ov[8];
  #pragma unroll
  for (int j = 0; j < 8; ++j){
    int k = hc * 8 + j;
    float v = 0.f;
    if (k < 16) v = mv[k * E_ + e] - b2[k * E_ + e];
    else if (k == 16){ float s = 0.f; for (int f = 0; f < F_; ++f) s += b2[f * E_ + e]; v = s; }
    ov[j] = f2bf(v);
  }
  *(uint4*)((char*)W2s + 16 * CHUNK_BYTES + c * 16) = *(uint4*)ov;
}

__global__ __launch_bounds__(NT, 2)
void ts_embed_main(const float* __restrict__ x, const int* __restrict__ mask,
                   const float* __restrict__ W1, const float* __restrict__ b1,
                   const unsigned short* __restrict__ W2s,
                   float* __restrict__ out){
  __shared__ __align__(16) short Abuf[2][BM * H_];   // 2 x 16 KB, swizzled
  __shared__ __align__(16) short Bbuf[2][E_ * H_];   // 2 x 32 KB, swizzled
  __shared__ __align__(16) float w1s[F_ * H_];
  __shared__ __align__(16) float b1s[F_ * H_];
  __shared__ __align__(16) float xs[BM * F_];
  __shared__ unsigned mrow[BM];

  const int tid  = threadIdx.x;
  const int lane = tid & 63;
  const int wid  = tid >> 6;
  const int wm   = wid >> 2, wn = wid & 3;
  const int rr   = lane & 15;
  const int klo  = (lane >> 4) << 3;
  const long rowBase = (long)blockIdx.x * BM;

  // ---- prologue staging
  ((float4*)xs)[tid] = ((const float4*)(x + rowBase * F_))[tid];
  if (tid < 256)      ((float4*)w1s)[tid]       = ((const float4*)W1)[tid];
  else                ((float4*)b1s)[tid - 256] = ((const float4*)b1)[tid - 256];
  if (tid < BM){
    const int4* mg = (const int4*)(mask + (rowBase + tid) * F_);
    unsigned bits = 0;
    #pragma unroll
    for (int q = 0; q < 4; ++q){
      int4 m = mg[q];
      bits |= (m.x != 0 ? 1u : 0u) << (q * 4 + 0);
      bits |= (m.y != 0 ? 1u : 0u) << (q * 4 + 1);
      bits |= (m.z != 0 ? 1u : 0u) << (q * 4 + 2);
      bits |= (m.w != 0 ? 1u : 0u) << (q * 4 + 3);
    }
    mrow[tid] = bits;
  }
  __syncthreads();

  const int r0 = tid >> 3, hcw = tid & 7;          // A-compute rows r0, r0+64
  const unsigned mb0 = mrow[r0], mb1 = mrow[r0 + 64];

  // async DMA one B chunk -> Bbuf[buf] (linear; wave-uniform LDS base + lane*16)
  auto stageB = [&](int chunk, int buf){
    const char* src = (const char*)W2s + chunk * CHUNK_BYTES + wid * 1024 + lane * 16;
    char* dst = (char*)Bbuf[0] + buf * (E_ * H_ * 2) + wid * 1024;
    #pragma unroll
    for (int kq = 0; kq < 4; ++kq)
      __builtin_amdgcn_global_load_lds((gas_ptr)(src + kq * 8192), (las_ptr)(dst + kq * 8192), 16, 0, 0);
  };

  auto computeA = [&](int fn, int buf){
    char* Ab = (char*)Abuf[0] + buf * (BM * H_ * 2);
    #pragma unroll
    for (int half = 0; half < 2; ++half){
      int r = r0 + half * 64;
      unsigned mb = half ? mb1 : mb0;
      float g[8];
      if (fn < F_){
        float xv  = xs[r * F_ + fn];
        float sel = ((mb >> fn) & 1u) ? 0.0f : 1.0f;
        const float4* wp = (const float4*)&w1s[fn * H_ + hcw * 8];
        const float4* bp = (const float4*)&b1s[fn * H_ + hcw * 8];
        float4 w0 = wp[0], w1v = wp[1], c0 = bp[0], c1 = bp[1];
        g[0] = sel * gelu_f(fmaf(xv, w0.x,  c0.x));
        g[1] = sel * gelu_f(fmaf(xv, w0.y,  c0.y));
        g[2] = sel * gelu_f(fmaf(xv, w0.z,  c0.z));
        g[3] = sel * gelu_f(fmaf(xv, w0.w,  c0.w));
        g[4] = sel * gelu_f(fmaf(xv, w1v.x, c1.x));
        g[5] = sel * gelu_f(fmaf(xv, w1v.y, c1.y));
        g[6] = sel * gelu_f(fmaf(xv, w1v.z, c1.z));
        g[7] = sel * gelu_f(fmaf(xv, w1v.w, c1.w));
      } else {
        #pragma unroll
        for (int j = 0; j < 8; ++j){
          int k = hcw * 8 + j;
          g[j] = (k < 16) ? (float)((mb >> k) & 1u) : (k == 16 ? 1.0f : 0.0f);
        }
      }
      union { unsigned u[4]; s16x8 v; } pk;
      pk.u[0] = cvtpk(g[0], g[1]); pk.u[1] = cvtpk(g[2], g[3]);
      pk.u[2] = cvtpk(g[4], g[5]); pk.u[3] = cvtpk(g[6], g[7]);
      int byte = (r * 128 + hcw * 16) ^ ((r & 7) << 4);
      *(s16x8*)(Ab + byte) = pk.v;
    }
  };

  // ---- pipeline fill
  stageB(0, 0);
  computeA(0, 0);
  __syncthreads();            // vmcnt(0) drain: B[0] resident, A[0] written

  f32x4 acc[4][4] = {};

  for (int f = 0; f < NCHUNK; ++f){
    // next-tile producer work first: DMA B(f+1), gelu A(f+1) -> other buffers.
    if (f < NCHUNK - 1){
      stageB(f + 1, (f + 1) & 1);
      computeA(f + 1, (f + 1) & 1);
    }
    // consumer: frag reads + MFMA for tile f (scheduler interleaves with gelu above)
    const char* Ab = (const char*)Abuf[0] + (f & 1) * (BM * H_ * 2);
    const char* Bb = (const char*)Bbuf[0] + (f & 1) * (E_ * H_ * 2);
    #pragma unroll
    for (int kk = 0; kk < 2; ++kk){
      s16x8 af[4], bfr[4];
      #pragma unroll
      for (int m = 0; m < 4; ++m){
        int r = wm * 64 + m * 16 + rr;
        int byte = (r * 128 + (kk * 32 + klo) * 2) ^ ((r & 7) << 4);
        af[m] = *(const s16x8*)(Ab + byte);
      }
      #pragma unroll
      for (int n = 0; n < 4; ++n){
        int e = wn * 64 + n * 16 + rr;
        int byte = (e * 128 + (kk * 32 + klo) * 2) ^ ((e & 7) << 4);
        bfr[n] = *(const s16x8*)(Bb + byte);
      }
      #pragma unroll
      for (int m = 0; m < 4; ++m)
        #pragma unroll
        for (int n = 0; n < 4; ++n)
          acc[m][n] = __builtin_amdgcn_mfma_f32_16x16x32_bf16(af[m], bfr[n], acc[m][n], 0, 0, 0);
    }
    // single barrier per feature: fences A/B dbuf swap AND drains next-tile DMA
    __syncthreads();
  }

  // ---- epilogue (bias+mask folded via chunk 16)
  const int rg = lane >> 4;
  #pragma unroll
  for (int m = 0; m < 4; ++m){
    #pragma unroll
    for (int n = 0; n < 4; ++n){
      int e = wn * 64 + n * 16 + rr;
      long r = rowBase + wm * 64 + m * 16 + rg * 4;
      #pragma unroll
      for (int j = 0; j < 4; ++j)
        out[(r + j) * E_ + e] = acc[m][n][j];
    }
  }
}

extern "C" void kernel_launch(void* const* d_in, const int* in_sizes, int n_in,
                              void* d_out, int out_size, void* d_ws, size_t ws_size,
                              hipStream_t stream) {
  const float* x    = (const float*)d_in[0];
  const int*   mask = (const int*)d_in[1];
  const float* W1   = (const float*)d_in[2];
  const float* b1   = (const float*)d_in[3];
  const float* W2   = (const float*)d_in[4];
  const float* b2   = (const float*)d_in[5];
  const float* mv   = (const float*)d_in[6];
  float* out = (float*)d_out;

  unsigned short* W2s = (unsigned short*)d_ws;   // 17 * 32768 B

  prep_w2<<<dim3(128), dim3(256), 0, stream>>>(W2, W2s);
  prep_tail<<<dim3(8), dim3(256), 0, stream>>>(b2, mv, W2s);
  ts_embed_main<<<dim3(BS_TOTAL / BM), dim3(NT), 0, stream>>>(x, mask, W1, b1, W2s, out);
}

// Round 4
// 46.537 us; speedup vs baseline: 1.6212x; 1.6177x over previous
//
#include <hip/hip_runtime.h>
#include <hip/hip_bf16.h>
#include <cstdint>
#include <math.h>

// B=32,S=2048,F=16,H=64,E=256.  BS=65536 rows.
// out[r,e] = sum_f ( mask[r,f] ? mv[f,e] : phi_{f,e}(x[r,f]) ),
//   phi_{f,e}(x) = sum_h gelu(x*W1+b1)*W2 + b2  — smooth 1-D function of x.
// r4: replace the 1024-deep gelu GEMM with a degree-14 Chebyshev expansion:
//   out[r,e] = sum_{f,d<=14} A[r, k(f,d)] * C[k(f,d), e],  K = 256 exactly.
//   A built IN-REGISTER (7 fma per fragment), C (128 KB bf16) resides in LDS whole.
//   Mask folded in: slot d=15 -> m_f * (mv-c0);  d=16 -> 1 * c0.
// k-layout bijection: kk=k>>5, klo2=(k>>3)&3, j=k&7;  f=(kk&3)*4+klo2, dm=(kk>>2)*8+j.

#define F_ 16
#define H_ 64
#define E_ 256
#define BM 128
#define NT 512
#define BS_TOTAL 65536
#define XSCALE 6.0f

#define CMAT_BYTES 131072                 // 256e x 256k x 2B, pre-swizzled image
#define PHI_OFF    CMAT_BYTES             // Phi f32 [16][16][256] = 256 KB

typedef __attribute__((ext_vector_type(8))) short s16x8;
typedef __attribute__((ext_vector_type(4))) float f32x4;
typedef const __attribute__((address_space(1))) unsigned int* gas_ptr;
typedef __attribute__((address_space(3))) unsigned int* las_ptr;

__device__ __forceinline__ unsigned short f2bf(float f){
  unsigned u = __builtin_bit_cast(unsigned, f);
  u += 0x7FFFu + ((u >> 16) & 1u);
  return (unsigned short)(u >> 16);
}
__device__ __forceinline__ unsigned cvtpk(float a, float b){
  unsigned r; asm("v_cvt_pk_bf16_f32 %0, %1, %2" : "=v"(r) : "v"(a), "v"(b)); return r;
}

// ---- prep 1: Phi[f][j][e] = phi_{f,e}(x_j) at 16 Chebyshev nodes (EXACT erf gelu)
__global__ void prep_phi(const float* __restrict__ W1, const float* __restrict__ b1,
                         const float* __restrict__ W2, const float* __restrict__ b2,
                         float* __restrict__ Phi){
  int f = blockIdx.x >> 2, jg = blockIdx.x & 3;
  __shared__ float hs[4][H_];
  int t = threadIdx.x;                       // 256
  {
    int jl = t >> 6, h = t & 63;
    float xj = XSCALE * cosf(3.14159265358979f * ((jg * 4 + jl) + 0.5f) / 16.0f);
    float z = xj * W1[f * H_ + h] + b1[f * H_ + h];
    hs[jl][h] = 0.5f * z * (1.0f + erff(z * 0.7071067811865475f));
  }
  __syncthreads();
  int e = t;
  const float4* w2p = (const float4*)(W2 + ((long)f * E_ + e) * H_);
  float b2v = b2[f * E_ + e];
  float ph[4] = {b2v, b2v, b2v, b2v};
  #pragma unroll
  for (int hq = 0; hq < 16; ++hq){
    float4 w = w2p[hq];
    #pragma unroll
    for (int jl = 0; jl < 4; ++jl){
      const float4 hv = *(const float4*)&hs[jl][hq * 4];
      ph[jl] += w.x * hv.x + w.y * hv.y + w.z * hv.z + w.w * hv.w;
    }
  }
  #pragma unroll
  for (int jl = 0; jl < 4; ++jl)
    Phi[((f * 16) + jg * 4 + jl) * E_ + e] = ph[jl];
}

// ---- prep 2: DCT -> c_0..c_14; write bf16 Cmat image (pre-inverse-swizzled)
__global__ void prep_cmat(const float* __restrict__ Phi, const float* __restrict__ mv,
                          unsigned short* __restrict__ Cmat){
  int f = blockIdx.x, e = threadIdx.x;
  __shared__ float ct[14][16];
  if (e < 224){
    int d = e >> 4, j = e & 15;
    ct[d][j] = cosf(3.14159265358979f * (d + 1) * (j + 0.5f) / 16.0f) * 0.125f; // 2/16
  }
  __syncthreads();
  float ph[16];
  float s = 0.f;
  #pragma unroll
  for (int j = 0; j < 16; ++j){ ph[j] = Phi[(f * 16 + j) * E_ + e]; s += ph[j]; }
  float c0 = s * 0.0625f;
  float vals[16];
  #pragma unroll
  for (int d = 0; d < 14; ++d){
    float c = 0.f;
    #pragma unroll
    for (int j = 0; j < 16; ++j) c += ph[j] * ct[d][j];
    vals[d] = c;
  }
  vals[14] = mv[f * E_ + e] - c0;
  vals[15] = c0;
  #pragma unroll
  for (int dq = 0; dq < 4; ++dq){
    int kk = (dq >> 1) * 4 + (f >> 2), klo2 = f & 3;
    int byte = ((e * 512 + kk * 64 + klo2 * 16) ^ ((e & 7) << 4)) + (dq & 1) * 8;
    unsigned w0 = (unsigned)f2bf(vals[dq*4+0]) | ((unsigned)f2bf(vals[dq*4+1]) << 16);
    unsigned w1 = (unsigned)f2bf(vals[dq*4+2]) | ((unsigned)f2bf(vals[dq*4+3]) << 16);
    uint2 wv = make_uint2(w0, w1);
    *(uint2*)((char*)Cmat + byte) = wv;
  }
}

// ---- main: K=256 GEMM, A in-register (Chebyshev recurrence), B whole in LDS
__global__ __launch_bounds__(NT, 2)
void ts_main(const float* __restrict__ x, const int* __restrict__ mask,
             const unsigned short* __restrict__ Cmat, float* __restrict__ out){
  __shared__ __align__(16) short Bls[E_ * 256];   // 128 KB

  const int tid = threadIdx.x, lane = tid & 63, wid = tid >> 6;
  const int wm = wid >> 2, wn = wid & 3;
  const int rr = lane & 15;
  const int q  = (lane >> 4) & 3;          // klo2: selects f within group of 4
  const int klo = (lane >> 4) << 3;        // element-k offset for frags
  const int rowBase = blockIdx.x * BM;

  // scalar x/mask loads first (so their waitcnt doesn't drain the DMAs)
  int rows[4];
  float xv[4][4]; int mk[4][4];
  #pragma unroll
  for (int m = 0; m < 4; ++m) rows[m] = rowBase + wm * 64 + m * 16 + rr;
  #pragma unroll
  for (int m = 0; m < 4; ++m)
    #pragma unroll
    for (int c = 0; c < 4; ++c){
      int idx = rows[m] * F_ + c * 4 + q;
      xv[m][c] = x[idx];
      mk[m][c] = mask[idx];
    }

  // stage whole Cmat -> LDS (linear image; swizzle already baked into Cmat)
  #pragma unroll
  for (int t = 0; t < 16; ++t){
    const char* src = (const char*)Cmat + tid * 16 + t * 8192;
    char* dst = (char*)Bls + wid * 1024 + t * 8192;
    __builtin_amdgcn_global_load_lds((gas_ptr)src, (las_ptr)dst, 16, 0, 0);
  }

  // u = clamp(x/6), chain seeds, mask selectors
  float u[4][4], tu[4][4], mf[4][4]; unsigned sz[4][4];
  #pragma unroll
  for (int m = 0; m < 4; ++m)
    #pragma unroll
    for (int c = 0; c < 4; ++c){
      float uu = xv[m][c] * (1.0f / XSCALE);
      uu = fminf(1.0f, fmaxf(-1.0f, uu));
      u[m][c] = uu; tu[m][c] = uu + uu;
      sz[m][c] = mk[m][c] ? 0u : 0xFFFFFFFFu;
      mf[m][c] = mk[m][c] ? 1.0f : 0.0f;
    }

  __syncthreads();    // drains DMAs; Bls resident for the whole kernel

  f32x4 acc[4][4] = {};
  float t7s[4][4], t8s[4][4];

  // kk = 0..3 : d = 1..8 windows (f = kk*4 + q)
  #pragma unroll
  for (int kk = 0; kk < 4; ++kk){
    s16x8 af[4];
    #pragma unroll
    for (int m = 0; m < 4; ++m){
      float uu = u[m][kk], t2 = tu[m][kk];
      float T1 = uu;
      float T2 = fmaf(t2, uu, -1.0f);
      float T3 = fmaf(t2, T2, -T1);
      float T4 = fmaf(t2, T3, -T2);
      float T5 = fmaf(t2, T4, -T3);
      float T6 = fmaf(t2, T5, -T4);
      float T7 = fmaf(t2, T6, -T5);
      float T8 = fmaf(t2, T7, -T6);
      t7s[m][kk] = T7; t8s[m][kk] = T8;
      unsigned z = sz[m][kk];
      union { unsigned w[4]; s16x8 v; } pk;
      pk.w[0] = cvtpk(T1, T2) & z;
      pk.w[1] = cvtpk(T3, T4) & z;
      pk.w[2] = cvtpk(T5, T6) & z;
      pk.w[3] = cvtpk(T7, T8) & z;
      af[m] = pk.v;
    }
    s16x8 bfr[4];
    #pragma unroll
    for (int n = 0; n < 4; ++n){
      int e = wn * 64 + n * 16 + rr;
      int byte = (e * 512 + (kk * 32 + klo) * 2) ^ ((e & 7) << 4);
      bfr[n] = *(const s16x8*)((const char*)Bls + byte);
    }
    #pragma unroll
    for (int m = 0; m < 4; ++m)
      #pragma unroll
      for (int n = 0; n < 4; ++n)
        acc[m][n] = __builtin_amdgcn_mfma_f32_16x16x32_bf16(af[m], bfr[n], acc[m][n], 0, 0, 0);
  }

  // kk = 4..7 : d = 9..14 + mask slot + ones slot (resume chains)
  #pragma unroll
  for (int c = 0; c < 4; ++c){
    const int kk = c + 4;
    s16x8 af[4];
    #pragma unroll
    for (int m = 0; m < 4; ++m){
      float t2 = tu[m][c];
      float T7 = t7s[m][c], T8 = t8s[m][c];
      float T9  = fmaf(t2, T8,  -T7);
      float T10 = fmaf(t2, T9,  -T8);
      float T11 = fmaf(t2, T10, -T9);
      float T12 = fmaf(t2, T11, -T10);
      float T13 = fmaf(t2, T12, -T11);
      float T14 = fmaf(t2, T13, -T12);
      unsigned z = sz[m][c];
      union { unsigned w[4]; s16x8 v; } pk;
      pk.w[0] = cvtpk(T9,  T10) & z;
      pk.w[1] = cvtpk(T11, T12) & z;
      pk.w[2] = cvtpk(T13, T14) & z;
      pk.w[3] = cvtpk(mf[m][c], 1.0f);      // m_f -> (mv-c0), 1 -> c0
      af[m] = pk.v;
    }
    s16x8 bfr[4];
    #pragma unroll
    for (int n = 0; n < 4; ++n){
      int e = wn * 64 + n * 16 + rr;
      int byte = (e * 512 + (kk * 32 + klo) * 2) ^ ((e & 7) << 4);
      bfr[n] = *(const s16x8*)((const char*)Bls + byte);
    }
    #pragma unroll
    for (int m = 0; m < 4; ++m)
      #pragma unroll
      for (int n = 0; n < 4; ++n)
        acc[m][n] = __builtin_amdgcn_mfma_f32_16x16x32_bf16(af[m], bfr[n], acc[m][n], 0, 0, 0);
  }

  // epilogue (r3-proven mapping)
  const int rg = lane >> 4;
  #pragma unroll
  for (int m = 0; m < 4; ++m){
    #pragma unroll
    for (int n = 0; n < 4; ++n){
      int e = wn * 64 + n * 16 + rr;
      int r = rowBase + wm * 64 + m * 16 + rg * 4;
      #pragma unroll
      for (int j = 0; j < 4; ++j)
        out[(long)(r + j) * E_ + e] = acc[m][n][j];
    }
  }
}

extern "C" void kernel_launch(void* const* d_in, const int* in_sizes, int n_in,
                              void* d_out, int out_size, void* d_ws, size_t ws_size,
                              hipStream_t stream) {
  const float* x    = (const float*)d_in[0];
  const int*   mask = (const int*)d_in[1];
  const float* W1   = (const float*)d_in[2];
  const float* b1   = (const float*)d_in[3];
  const float* W2   = (const float*)d_in[4];
  const float* b2   = (const float*)d_in[5];
  const float* mv   = (const float*)d_in[6];
  float* out = (float*)d_out;

  unsigned short* Cmat = (unsigned short*)d_ws;
  float* Phi = (float*)((char*)d_ws + PHI_OFF);

  prep_phi<<<dim3(64), dim3(256), 0, stream>>>(W1, b1, W2, b2, Phi);
  prep_cmat<<<dim3(16), dim3(256), 0, stream>>>(Phi, mv, Cmat);
  ts_main<<<dim3(BS_TOTAL / BM), dim3(NT), 0, stream>>>(x, mask, Cmat, out);
}

// Round 5
// 34.280 us; speedup vs baseline: 2.2008x; 1.3575x over previous
//
#include <hip/hip_runtime.h>
#include <hip/hip_bf16.h>
#include <cstdint>
#include <math.h>

// B=32,S=2048,F=16,H=64,E=256.  BS=65536 rows.
// out[r,e] = sum_f ( mask[r,f] ? mv[f,e] : phi_{f,e}(x[r,f]) ),
//   phi_{f,e}(x) = sum_h gelu(x*W1+b1)*W2 + b2  (smooth 1-D in x).
// Degree-14 Chebyshev per (f,e):  out = sum_{f,d} T_d(x_f/6) * c_d[f,e],  K=256 GEMM.
// r5: barrier-free main kernel. B (Cmat, 128 KB) is IDENTICAL for all blocks and
// pre-packed in exact MFMA-fragment order -> each B-frag is one contiguous 1 KB
// coalesced global load (L2-resident). No LDS, no __syncthreads in the main kernel.
// A built in-register: thread's 4 features are contiguous (f = q*4+c) -> float4 x loads.
// Mask folded as extra K-slots: j6 -> m_f*(mv-c0), j7 -> 1*c0.
//
// k-bijection: k = kk*32 + q*8 + j ;  c = kk&3, g = kk>>2 ;  f = q*4 + c ; dm = g*8 + j.
// Cmat slot (kk, eb, lane) at byte ((kk*16+eb)*64+lane)*16, lane = q*16 + (e&15).

#define F_ 16
#define H_ 64
#define E_ 256
#define BM 128
#define NT 512
#define BS_TOTAL 65536
#define XSCALE 6.0f

typedef __attribute__((ext_vector_type(8))) short s16x8;
typedef __attribute__((ext_vector_type(4))) float f32x4;

__device__ __forceinline__ unsigned short f2bf(float f){
  unsigned u = __builtin_bit_cast(unsigned, f);
  u += 0x7FFFu + ((u >> 16) & 1u);
  return (unsigned short)(u >> 16);
}
__device__ __forceinline__ unsigned cvtpk(float a, float b){
  unsigned r; asm("v_cvt_pk_bf16_f32 %0, %1, %2" : "=v"(r) : "v"(a), "v"(b)); return r;
}

// ---- single prep: per f (16 blocks), compute phi at 16 Chebyshev nodes (exact erf
// gelu), DCT -> c_0..c_14, write frag-packed bf16 Cmat.
__global__ __launch_bounds__(256)
void prep_cmat(const float* __restrict__ W1, const float* __restrict__ b1,
               const float* __restrict__ W2, const float* __restrict__ b2,
               const float* __restrict__ mv, unsigned short* __restrict__ Cmat){
  const int f = blockIdx.x, t = threadIdx.x;
  __shared__ float hs[16][H_];     // gelu(x_j*W1+b1) at the 16 nodes
  __shared__ float ct[14][16];     // DCT basis * 2/16

  #pragma unroll
  for (int s = 0; s < 4; ++s){
    int idx = t + s * 256;         // 0..1023
    int j = idx >> 6, h = idx & 63;
    float xj = XSCALE * cosf(3.14159265358979f * (j + 0.5f) / 16.0f);
    float z = xj * W1[f * H_ + h] + b1[f * H_ + h];
    hs[j][h] = 0.5f * z * (1.0f + erff(z * 0.7071067811865475f));
  }
  if (t < 224){
    int d = t >> 4, j = t & 15;
    ct[d][j] = cosf(3.14159265358979f * (d + 1) * (j + 0.5f) / 16.0f) * 0.125f;
  }
  __syncthreads();

  const int e = t;
  const float4* w2p = (const float4*)(W2 + ((long)f * E_ + e) * H_);
  float b2v = b2[f * E_ + e];
  float ph[16];
  #pragma unroll
  for (int j = 0; j < 16; ++j) ph[j] = b2v;
  #pragma unroll
  for (int hq = 0; hq < 16; ++hq){
    float4 w = w2p[hq];
    #pragma unroll
    for (int j = 0; j < 16; ++j){
      const float4 hv = *(const float4*)&hs[j][hq * 4];
      ph[j] += w.x * hv.x + w.y * hv.y + w.z * hv.z + w.w * hv.w;
    }
  }
  float s0 = 0.f;
  #pragma unroll
  for (int j = 0; j < 16; ++j) s0 += ph[j];
  float c0 = s0 * 0.0625f;

  float vals[16];
  #pragma unroll
  for (int d = 0; d < 14; ++d){
    float c = 0.f;
    #pragma unroll
    for (int j = 0; j < 16; ++j) c += ph[j] * ct[d][j];
    vals[d] = c;
  }
  vals[14] = mv[f * E_ + e] - c0;   // pairs with A slot j6 = m_f
  vals[15] = c0;                    // pairs with A slot j7 = 1

  const int lane = (f >> 2) * 16 + (e & 15);   // q = f>>2
  const int eb = e >> 4;
  #pragma unroll
  for (int g = 0; g < 2; ++g){
    int kk = g * 4 + (f & 3);
    unsigned w[4];
    w[0] = (unsigned)f2bf(vals[g*8+0]) | ((unsigned)f2bf(vals[g*8+1]) << 16);
    w[1] = (unsigned)f2bf(vals[g*8+2]) | ((unsigned)f2bf(vals[g*8+3]) << 16);
    w[2] = (unsigned)f2bf(vals[g*8+4]) | ((unsigned)f2bf(vals[g*8+5]) << 16);
    w[3] = (unsigned)f2bf(vals[g*8+6]) | ((unsigned)f2bf(vals[g*8+7]) << 16);
    long byte = ((long)(kk * 16 + eb) * 64 + lane) * 16;
    *(uint4*)((char*)Cmat + byte) = *(uint4*)w;
  }
}

// ---- main: K=256 GEMM, A in-register, B direct from global (L2), no LDS/barriers
__global__ __launch_bounds__(NT)
void ts_main(const float* __restrict__ x, const int* __restrict__ mask,
             const unsigned short* __restrict__ Cmat, float* __restrict__ out){
  const int tid = threadIdx.x, lane = tid & 63, wid = tid >> 6;
  const int wm = wid >> 2, wn = wid & 3;
  const int rr = lane & 15;
  const int q  = lane >> 4;               // 0..3: this lane's feature group & k-quarter
  const int rowBase = blockIdx.x * BM;

  int rows[4];
  #pragma unroll
  for (int m = 0; m < 4; ++m) rows[m] = rowBase + wm * 64 + m * 16 + rr;

  // coalesced x/mask loads: features q*4..q*4+3 of each row
  float4 x4[4]; int4 mk4[4];
  #pragma unroll
  for (int m = 0; m < 4; ++m){
    x4[m]  = *(const float4*)&x[rows[m] * F_ + q * 4];
    mk4[m] = *(const int4*)&mask[rows[m] * F_ + q * 4];
  }

  const s16x8* C8 = (const s16x8*)Cmat;   // slot index = (kk*16 + eblk)*64 + lane
  f32x4 acc[4][4] = {};

  #pragma unroll
  for (int c = 0; c < 4; ++c){
    // B frags for kk=c (d 1..8) and kk=c+4 (d 9..14, mask, c0)
    s16x8 blo[4], bhi[4];
    #pragma unroll
    for (int n = 0; n < 4; ++n){
      blo[n] = C8[((c    ) * 16 + wn * 4 + n) * 64 + lane];
      bhi[n] = C8[((c + 4) * 16 + wn * 4 + n) * 64 + lane];
    }
    // A frags: full Chebyshev chain for feature q*4+c of each row
    s16x8 alo[4], ahi[4];
    #pragma unroll
    for (int m = 0; m < 4; ++m){
      float xv = ((const float*)&x4[m])[c];
      int  mkv = ((const int*)&mk4[m])[c];
      float uu = xv * (1.0f / XSCALE);
      uu = fminf(1.0f, fmaxf(-1.0f, uu));
      float t2 = uu + uu;
      float T1 = uu;
      float T2 = fmaf(t2, T1, -1.0f);
      float T3 = fmaf(t2, T2, -T1);
      float T4 = fmaf(t2, T3, -T2);
      float T5 = fmaf(t2, T4, -T3);
      float T6 = fmaf(t2, T5, -T4);
      float T7 = fmaf(t2, T6, -T5);
      float T8 = fmaf(t2, T7, -T6);
      float T9  = fmaf(t2, T8,  -T7);
      float T10 = fmaf(t2, T9,  -T8);
      float T11 = fmaf(t2, T10, -T9);
      float T12 = fmaf(t2, T11, -T10);
      float T13 = fmaf(t2, T12, -T11);
      float T14 = fmaf(t2, T13, -T12);
      unsigned z = mkv ? 0u : 0xFFFFFFFFu;
      float mf = mkv ? 1.0f : 0.0f;
      union { unsigned w[4]; s16x8 v; } pl, ph;
      pl.w[0] = cvtpk(T1, T2) & z;  pl.w[1] = cvtpk(T3, T4) & z;
      pl.w[2] = cvtpk(T5, T6) & z;  pl.w[3] = cvtpk(T7, T8) & z;
      ph.w[0] = cvtpk(T9, T10) & z; ph.w[1] = cvtpk(T11, T12) & z;
      ph.w[2] = cvtpk(T13, T14) & z; ph.w[3] = cvtpk(mf, 1.0f);
      alo[m] = pl.v; ahi[m] = ph.v;
    }
    #pragma unroll
    for (int m = 0; m < 4; ++m)
      #pragma unroll
      for (int n = 0; n < 4; ++n)
        acc[m][n] = __builtin_amdgcn_mfma_f32_16x16x32_bf16(alo[m], blo[n], acc[m][n], 0, 0, 0);
    #pragma unroll
    for (int m = 0; m < 4; ++m)
      #pragma unroll
      for (int n = 0; n < 4; ++n)
        acc[m][n] = __builtin_amdgcn_mfma_f32_16x16x32_bf16(ahi[m], bhi[n], acc[m][n], 0, 0, 0);
  }

  // epilogue (r4-proven C/D mapping)
  const int rg = lane >> 4;
  #pragma unroll
  for (int m = 0; m < 4; ++m){
    #pragma unroll
    for (int n = 0; n < 4; ++n){
      int e = wn * 64 + n * 16 + rr;
      int r = rowBase + wm * 64 + m * 16 + rg * 4;
      #pragma unroll
      for (int j = 0; j < 4; ++j)
        out[(long)(r + j) * E_ + e] = acc[m][n][j];
    }
  }
}

extern "C" void kernel_launch(void* const* d_in, const int* in_sizes, int n_in,
                              void* d_out, int out_size, void* d_ws, size_t ws_size,
                              hipStream_t stream) {
  const float* x    = (const float*)d_in[0];
  const int*   mask = (const int*)d_in[1];
  const float* W1   = (const float*)d_in[2];
  const float* b1   = (const float*)d_in[3];
  const float* W2   = (const float*)d_in[4];
  const float* b2   = (const float*)d_in[5];
  const float* mv   = (const float*)d_in[6];
  float* out = (float*)d_out;

  unsigned short* Cmat = (unsigned short*)d_ws;   // 128 KB frag-packed image

  prep_cmat<<<dim3(F_), dim3(256), 0, stream>>>(W1, b1, W2, b2, mv, Cmat);
  ts_main<<<dim3(BS_TOTAL / BM), dim3(NT), 0, stream>>>(x, mask, Cmat, out);
}